// Round 2
// baseline (1205.910 us; speedup 1.0000x reference)
//
#include <hip/hip_runtime.h>
#include <hip/hip_bf16.h>

#define D 128
#define NPB 64      // nodes per GEMM block
#define KT 32       // k-tile
#define MIN_BLOCKS 512

// ---------------- bf16 helpers (manual, RN-even) ----------------
__device__ __forceinline__ float bf16_to_f(unsigned int u) {
    union { unsigned int i; float f; } c; c.i = u << 16; return c.f;
}
__device__ __forceinline__ unsigned short f_to_bf16(float f) {
    union { float f; unsigned int i; } c; c.f = f;
    unsigned int r = c.i + 0x7FFFu + ((c.i >> 16) & 1u);
    return (unsigned short)(r >> 16);
}

// ---------------- runtime dtype detection ----------------
// flag[0]: edge_index is int64?   flag[1]: float tensors are bf16?
__global__ void detect_kernel(const unsigned short* __restrict__ xr,
                              const int* __restrict__ er, int* __restrict__ flag) {
    // x dtype: probe EVEN uint16 words. bf16 N(0,1) data -> exponent field clustered;
    // fp32 data -> even words are low mantissa bits (uniform random).
    int plaus = 0;
    for (int i = 0; i < 64; ++i) {
        unsigned short u = xr[2 * i];
        int e = (u >> 7) & 0xFF;          // bf16 exponent field
        if (e >= 0x74 && e <= 0x82) plaus++;   // |v| in ~[2^-11, 16)
    }
    flag[1] = (plaus >= 32) ? 1 : 0;
    // edge dtype: int64 little-endian values < 2^31 -> odd int32 words all zero.
    int zeros = 0;
    for (int i = 1; i < 128; i += 2) zeros += (er[i] == 0);
    flag[0] = (zeros >= 60) ? 1 : 0;
}

__device__ __forceinline__ int load_idx(const void* p, long long i, int is64) {
    if (is64) return (int)((const long long*)p)[i];
    return ((const int*)p)[i];
}

// ---------------- conversions ----------------
__global__ void cvt_x_kernel(const void* __restrict__ src, const int* __restrict__ flag,
                             unsigned short* __restrict__ dst, int n) {
    int is_bf16 = flag[1];
    int i = blockIdx.x * blockDim.x + threadIdx.x;
    int stride = gridDim.x * blockDim.x;
    if (is_bf16) {
        const unsigned short* s = (const unsigned short*)src;
        for (; i < n; i += stride) dst[i] = s[i];
    } else {
        const float* s = (const float*)src;
        for (; i < n; i += stride) dst[i] = f_to_bf16(s[i]);
    }
}

__global__ void cvt_f_kernel(const void* __restrict__ src, const int* __restrict__ flag,
                             float* __restrict__ dst, int n) {
    int is_bf16 = flag[1];
    int i = blockIdx.x * blockDim.x + threadIdx.x;
    int stride = gridDim.x * blockDim.x;
    if (is_bf16) {
        const unsigned short* s = (const unsigned short*)src;
        for (; i < n; i += stride) dst[i] = bf16_to_f(s[i]);
    } else {
        const float* s = (const float*)src;
        for (; i < n; i += stride) dst[i] = s[i];
    }
}

// ---------------- CSR build ----------------
__global__ void hist_kernel(const void* __restrict__ eidx, const int* __restrict__ flag,
                            int* __restrict__ cnt, int E, int N) {
    int is64 = flag[0];
    int e = blockIdx.x * blockDim.x + threadIdx.x;
    if (e < E) {
        int d = load_idx(eidx, (long long)E + e, is64);
        if ((unsigned)d < (unsigned)N) atomicAdd(&cnt[d], 1);
    }
}

__global__ __launch_bounds__(1024)
void scan_kernel(const int* __restrict__ cnt, int* __restrict__ offsets,
                 int* __restrict__ cursor, int N, int E) {
    __shared__ int partials[1024];
    int tid = threadIdx.x;
    int chunk = (N + 1023) >> 10;
    int start = tid * chunk;
    int end = min(start + chunk, N);
    int sum = 0;
    for (int i = start; i < end; ++i) sum += cnt[i];
    partials[tid] = sum;
    __syncthreads();
    for (int off = 1; off < 1024; off <<= 1) {
        int v = (tid >= off) ? partials[tid - off] : 0;
        __syncthreads();
        partials[tid] += v;
        __syncthreads();
    }
    int run = partials[tid] - sum;   // exclusive prefix of this chunk
    for (int i = start; i < end; ++i) {
        offsets[i] = run;
        cursor[i] = run;
        run += cnt[i];
    }
    if (tid == 0) offsets[N] = E;
}

__global__ void fill_kernel(const void* __restrict__ eidx, const int* __restrict__ flag,
                            int* __restrict__ cursor, int* __restrict__ srcs_sorted,
                            int E, int N) {
    int is64 = flag[0];
    int e = blockIdx.x * blockDim.x + threadIdx.x;
    if (e < E) {
        int s = load_idx(eidx, e, is64);
        int d = load_idx(eidx, (long long)E + e, is64);
        if ((unsigned)d < (unsigned)N) {
            int p = atomicAdd(&cursor[d], 1);
            srcs_sorted[p] = s;
        }
    }
}

// ---------------- mean aggregation (gather via CSR), bf16 rows ----------------
// 16 lanes per node, uint4 (8 bf16) per lane -> 256B coalesced row reads.
__global__ void agg_kernel(const unsigned short* __restrict__ xb, const int* __restrict__ offsets,
                           const int* __restrict__ srcs, unsigned short* __restrict__ meanb, int N) {
    int g = blockIdx.x * blockDim.x + threadIdx.x;
    int node = g >> 4;
    int lane = g & 15;
    if (node >= N) return;
    int beg = offsets[node], end = offsets[node + 1];
    float acc[8];
#pragma unroll
    for (int i = 0; i < 8; ++i) acc[i] = 0.f;
    const uint4* xp = (const uint4*)xb;   // row = 16 uint4
    for (int j = beg; j < end; ++j) {
        uint4 v = xp[(size_t)srcs[j] * 16 + lane];
        acc[0] += bf16_to_f(v.x & 0xFFFFu); acc[1] += bf16_to_f(v.x >> 16);
        acc[2] += bf16_to_f(v.y & 0xFFFFu); acc[3] += bf16_to_f(v.y >> 16);
        acc[4] += bf16_to_f(v.z & 0xFFFFu); acc[5] += bf16_to_f(v.z >> 16);
        acc[6] += bf16_to_f(v.w & 0xFFFFu); acc[7] += bf16_to_f(v.w >> 16);
    }
    float inv = (end > beg) ? 1.0f / (float)(end - beg) : 0.0f;
    uint4 o;
    o.x = (unsigned)f_to_bf16(acc[0] * inv) | ((unsigned)f_to_bf16(acc[1] * inv) << 16);
    o.y = (unsigned)f_to_bf16(acc[2] * inv) | ((unsigned)f_to_bf16(acc[3] * inv) << 16);
    o.z = (unsigned)f_to_bf16(acc[4] * inv) | ((unsigned)f_to_bf16(acc[5] * inv) << 16);
    o.w = (unsigned)f_to_bf16(acc[6] * inv) | ((unsigned)f_to_bf16(acc[7] * inv) << 16);
    ((uint4*)meanb)[(size_t)node * 16 + lane] = o;
}

// ---------------- fused dual GEMM: out = mean@Wl^T + x@Wr^T + b (+relu) ----------------
// Block: 256 threads, 64 nodes x 128 cols. Thread: 8 nodes x 4 cols. fp32 accumulate.
__global__ __launch_bounds__(256)
void gemm_kernel(const unsigned short* __restrict__ meanb, const unsigned short* __restrict__ xb,
                 const float* __restrict__ Wl, const float* __restrict__ bl,
                 const float* __restrict__ Wr, unsigned short* __restrict__ outb,
                 int N, int relu) {
    __shared__ float Wt[KT][D + 4];     // [kk][c], transposed W tile
    __shared__ float At[KT][NPB + 4];   // [kk][j], transposed A tile

    const int tid = threadIdx.x;
    const int c4 = (tid & 31) * 4;
    const int jg = tid >> 5;
    const int node0 = blockIdx.x * NPB;

    float acc[8][4];
#pragma unroll
    for (int j = 0; j < 8; ++j)
#pragma unroll
        for (int c = 0; c < 4; ++c) acc[j][c] = 0.f;

    for (int kt = 0; kt < 2 * D; kt += KT) {
        const float* W = (kt < D) ? Wl : Wr;
        const unsigned short* A = (kt < D) ? meanb : xb;
        const int k0 = (kt < D) ? kt : (kt - D);

        for (int i = tid; i < KT * D; i += 256) {
            int kk = i & (KT - 1);
            int cc = i >> 5;
            Wt[kk][cc] = W[(size_t)cc * D + k0 + kk];
        }
        for (int i = tid; i < KT * NPB; i += 256) {
            int kk = i & (KT - 1);
            int j = i >> 5;
            int n = node0 + j;
            At[kk][j] = (n < N) ? bf16_to_f(A[(size_t)n * D + k0 + kk]) : 0.f;
        }
        __syncthreads();

        for (int kk = 0; kk < KT; ++kk) {
            float4 w = *(const float4*)&Wt[kk][c4];
            float4 a0 = *(const float4*)&At[kk][jg * 8];
            float4 a1 = *(const float4*)&At[kk][jg * 8 + 4];
            float av[8] = {a0.x, a0.y, a0.z, a0.w, a1.x, a1.y, a1.z, a1.w};
#pragma unroll
            for (int j2 = 0; j2 < 8; ++j2) {
                acc[j2][0] += av[j2] * w.x;
                acc[j2][1] += av[j2] * w.y;
                acc[j2][2] += av[j2] * w.z;
                acc[j2][3] += av[j2] * w.w;
            }
        }
        __syncthreads();
    }

    float4 b = *(const float4*)&bl[c4];
#pragma unroll
    for (int j2 = 0; j2 < 8; ++j2) {
        int n = node0 + jg * 8 + j2;
        if (n < N) {
            float v0 = acc[j2][0] + b.x;
            float v1 = acc[j2][1] + b.y;
            float v2 = acc[j2][2] + b.z;
            float v3 = acc[j2][3] + b.w;
            if (relu) {
                v0 = fmaxf(v0, 0.f); v1 = fmaxf(v1, 0.f);
                v2 = fmaxf(v2, 0.f); v3 = fmaxf(v3, 0.f);
            }
            uint2 o;
            o.x = (unsigned)f_to_bf16(v0) | ((unsigned)f_to_bf16(v1) << 16);
            o.y = (unsigned)f_to_bf16(v2) | ((unsigned)f_to_bf16(v3) << 16);
            *(uint2*)&outb[(size_t)n * D + c4] = o;
        }
    }
}

// ---------------- column-wise min reduction ----------------
__global__ void min1_kernel(const unsigned short* __restrict__ xb, float* __restrict__ partial, int N) {
    int col = threadIdx.x;   // 128 threads
    float m = 3.402823466e38f;
    for (int n = blockIdx.x; n < N; n += gridDim.x)
        m = fminf(m, bf16_to_f(xb[(size_t)n * D + col]));
    partial[(size_t)blockIdx.x * D + col] = m;
}

__global__ void min2_kernel(const float* __restrict__ partial, const int* __restrict__ flag,
                            void* __restrict__ out) {
    int col = threadIdx.x;
    float m = 3.402823466e38f;
    for (int b = 0; b < MIN_BLOCKS; ++b)
        m = fminf(m, partial[(size_t)b * D + col]);
    if (flag[1]) ((unsigned short*)out)[col] = f_to_bf16(m);
    else         ((float*)out)[col] = m;
}

// ---------------- launch ----------------
extern "C" void kernel_launch(void* const* d_in, const int* in_sizes, int n_in,
                              void* d_out, int out_size, void* d_ws, size_t ws_size,
                              hipStream_t stream) {
    const void* x0   = d_in[0];
    const void* eidx = d_in[1];
    const void* Wl0  = d_in[2];
    const void* bl0  = d_in[3];
    const void* Wr0  = d_in[4];

    const int N = in_sizes[0] / D;          // 100000
    const int E = in_sizes[1] / 2;          // 1600000
    const int L = in_sizes[2] / (D * D);    // 3

    char* ws = (char*)d_ws;
    size_t off = 0;
    auto alloc = [&](size_t bytes) -> void* {
        void* p = ws + off;
        off += (bytes + 255) & ~(size_t)255;
        return p;
    };
    unsigned short* xb    = (unsigned short*)alloc((size_t)N * D * 2);  // 25.6 MB
    unsigned short* bufA  = (unsigned short*)alloc((size_t)N * D * 2);  // 25.6 MB
    unsigned short* meanb = (unsigned short*)alloc((size_t)N * D * 2);  // 25.6 MB
    int*   cnt     = (int*)alloc((size_t)N * sizeof(int));
    int*   offsets = (int*)alloc((size_t)(N + 1) * sizeof(int));
    int*   cursor  = (int*)alloc((size_t)N * sizeof(int));
    int*   srcs    = (int*)alloc((size_t)E * sizeof(int));
    int*   flag    = (int*)alloc(256);
    float* Wlf     = (float*)alloc((size_t)L * D * D * sizeof(float));
    float* blf     = (float*)alloc((size_t)L * D * sizeof(float));
    float* Wrf     = (float*)alloc((size_t)L * D * D * sizeof(float));
    float* partial = (float*)alloc((size_t)MIN_BLOCKS * D * sizeof(float));
    (void)ws_size; (void)n_in; (void)out_size;

    hipMemsetAsync(cnt, 0, (size_t)N * sizeof(int), stream);

    detect_kernel<<<1, 1, 0, stream>>>((const unsigned short*)x0, (const int*)eidx, flag);

    cvt_x_kernel<<<2048, 256, 0, stream>>>(x0, flag, xb, N * D);
    cvt_f_kernel<<<256, 256, 0, stream>>>(Wl0, flag, Wlf, L * D * D);
    cvt_f_kernel<<<8, 256, 0, stream>>>(bl0, flag, blf, L * D);
    cvt_f_kernel<<<256, 256, 0, stream>>>(Wr0, flag, Wrf, L * D * D);

    hist_kernel<<<(E + 255) / 256, 256, 0, stream>>>(eidx, flag, cnt, E, N);
    scan_kernel<<<1, 1024, 0, stream>>>(cnt, offsets, cursor, N, E);
    fill_kernel<<<(E + 255) / 256, 256, 0, stream>>>(eidx, flag, cursor, srcs, E, N);

    unsigned short* cur = xb;
    unsigned short* nxt = bufA;
    for (int l = 0; l < L; ++l) {
        int agg_blocks = (N * 16 + 255) / 256;
        agg_kernel<<<agg_blocks, 256, 0, stream>>>(cur, offsets, srcs, meanb, N);
        gemm_kernel<<<(N + NPB - 1) / NPB, 256, 0, stream>>>(
            meanb, cur, Wlf + (size_t)l * D * D, blf + (size_t)l * D,
            Wrf + (size_t)l * D * D, nxt, N, (l < L - 1) ? 1 : 0);
        unsigned short* t = cur; cur = nxt; nxt = t;
    }

    min1_kernel<<<MIN_BLOCKS, D, 0, stream>>>(cur, partial, N);
    min2_kernel<<<1, D, 0, stream>>>(partial, flag, (void*)d_out);
}

// Round 3
// 982.991 us; speedup vs baseline: 1.2268x; 1.2268x over previous
//
#include <hip/hip_runtime.h>
#include <hip/hip_bf16.h>

#define D 128
#define NPB 64      // nodes per GEMM block
#define KT 32       // k-tile
#define MIN_BLOCKS 512
#define SCAN_C 512  // elements per scan block (2 per thread, 256 threads)

// ---------------- bf16 helpers (manual, RN-even) ----------------
__device__ __forceinline__ float bf16_to_f(unsigned int u) {
    union { unsigned int i; float f; } c; c.i = u << 16; return c.f;
}
__device__ __forceinline__ unsigned short f_to_bf16(float f) {
    union { float f; unsigned int i; } c; c.f = f;
    unsigned int r = c.i + 0x7FFFu + ((c.i >> 16) & 1u);
    return (unsigned short)(r >> 16);
}

// ---------------- runtime dtype detection ----------------
// flag[0]: edge_index is int64?   flag[1]: float tensors are bf16?
__global__ void detect_kernel(const unsigned short* __restrict__ xr,
                              const int* __restrict__ er, int* __restrict__ flag) {
    int plaus = 0;
    for (int i = 0; i < 64; ++i) {
        unsigned short u = xr[2 * i];
        int e = (u >> 7) & 0xFF;
        if (e >= 0x74 && e <= 0x82) plaus++;
    }
    flag[1] = (plaus >= 32) ? 1 : 0;
    int zeros = 0;
    for (int i = 1; i < 128; i += 2) zeros += (er[i] == 0);
    flag[0] = (zeros >= 60) ? 1 : 0;
}

__device__ __forceinline__ int load_idx(const void* p, long long i, int is64) {
    if (is64) return (int)((const long long*)p)[i];
    return ((const int*)p)[i];
}

// ---------------- conversions ----------------
__global__ void cvt_x_kernel(const void* __restrict__ src, const int* __restrict__ flag,
                             unsigned short* __restrict__ dst, int n) {
    int is_bf16 = flag[1];
    int i = blockIdx.x * blockDim.x + threadIdx.x;
    int stride = gridDim.x * blockDim.x;
    if (is_bf16) {
        const unsigned short* s = (const unsigned short*)src;
        for (; i < n; i += stride) dst[i] = s[i];
    } else {
        const float* s = (const float*)src;
        for (; i < n; i += stride) dst[i] = f_to_bf16(s[i]);
    }
}

__global__ void cvt_f_kernel(const void* __restrict__ src, const int* __restrict__ flag,
                             float* __restrict__ dst, int n) {
    int is_bf16 = flag[1];
    int i = blockIdx.x * blockDim.x + threadIdx.x;
    int stride = gridDim.x * blockDim.x;
    if (is_bf16) {
        const unsigned short* s = (const unsigned short*)src;
        for (; i < n; i += stride) dst[i] = bf16_to_f(s[i]);
    } else {
        const float* s = (const float*)src;
        for (; i < n; i += stride) dst[i] = s[i];
    }
}

// ---------------- CSR build ----------------
__global__ void hist_kernel(const void* __restrict__ eidx, const int* __restrict__ flag,
                            int* __restrict__ cnt, int E, int N) {
    int is64 = flag[0];
    int e = blockIdx.x * blockDim.x + threadIdx.x;
    if (e < E) {
        int d = load_idx(eidx, (long long)E + e, is64);
        if ((unsigned)d < (unsigned)N) atomicAdd(&cnt[d], 1);
    }
}

// -------- parallel 3-phase exclusive scan over cnt[0..N) --------
__global__ void scan1_kernel(const int* __restrict__ cnt, int* __restrict__ blockSums, int N) {
    __shared__ int red[256];
    int base = blockIdx.x * SCAN_C;
    int t = threadIdx.x;
    int s = 0;
    if (base + t < N) s += cnt[base + t];
    if (base + t + 256 < N) s += cnt[base + t + 256];
    red[t] = s;
    __syncthreads();
    for (int off = 128; off > 0; off >>= 1) {
        if (t < off) red[t] += red[t + off];
        __syncthreads();
    }
    if (t == 0) blockSums[blockIdx.x] = red[0];
}

__global__ void scan2_kernel(int* __restrict__ blockSums, int nb) {
    __shared__ int sh[256];
    int t = threadIdx.x;
    int orig = (t < nb) ? blockSums[t] : 0;
    sh[t] = orig;
    __syncthreads();
    for (int off = 1; off < 256; off <<= 1) {
        int v = (t >= off) ? sh[t - off] : 0;
        __syncthreads();
        sh[t] += v;
        __syncthreads();
    }
    if (t < nb) blockSums[t] = sh[t] - orig;   // exclusive
}

__global__ void scan3_kernel(const int* __restrict__ cnt, const int* __restrict__ blockBase,
                             int* __restrict__ offsets, int* __restrict__ cursor, int N, int E) {
    __shared__ int sh[SCAN_C];
    int base = blockIdx.x * SCAN_C;
    int t = threadIdx.x;
    int v0 = (base + t < N) ? cnt[base + t] : 0;
    int v1 = (base + t + 256 < N) ? cnt[base + t + 256] : 0;
    sh[t] = v0;
    sh[t + 256] = v1;
    __syncthreads();
    for (int off = 1; off < SCAN_C; off <<= 1) {
        int a = (t >= off) ? sh[t - off] : 0;
        int b = (t + 256 >= off) ? sh[t + 256 - off] : 0;
        __syncthreads();
        sh[t] += a;
        sh[t + 256] += b;
        __syncthreads();
    }
    int bb = blockBase[blockIdx.x];
    if (base + t < N) {
        int e = bb + sh[t] - v0;
        offsets[base + t] = e;
        cursor[base + t] = e;
    }
    if (base + t + 256 < N) {
        int e = bb + sh[t + 256] - v1;
        offsets[base + t + 256] = e;
        cursor[base + t + 256] = e;
    }
    if (blockIdx.x == 0 && t == 0) offsets[N] = E;
}

__global__ void fill_kernel(const void* __restrict__ eidx, const int* __restrict__ flag,
                            int* __restrict__ cursor, int* __restrict__ srcs_sorted,
                            int E, int N) {
    int is64 = flag[0];
    int e = blockIdx.x * blockDim.x + threadIdx.x;
    if (e < E) {
        int s = load_idx(eidx, e, is64);
        int d = load_idx(eidx, (long long)E + e, is64);
        if ((unsigned)d < (unsigned)N) {
            int p = atomicAdd(&cursor[d], 1);
            srcs_sorted[p] = s;
        }
    }
}

// ---------------- mean aggregation (gather via CSR), bf16 rows ----------------
__global__ void agg_kernel(const unsigned short* __restrict__ xb, const int* __restrict__ offsets,
                           const int* __restrict__ srcs, unsigned short* __restrict__ meanb, int N) {
    int g = blockIdx.x * blockDim.x + threadIdx.x;
    int node = g >> 4;
    int lane = g & 15;
    if (node >= N) return;
    int beg = offsets[node], end = offsets[node + 1];
    float acc[8];
#pragma unroll
    for (int i = 0; i < 8; ++i) acc[i] = 0.f;
    const uint4* xp = (const uint4*)xb;   // row = 16 uint4
    for (int j = beg; j < end; ++j) {
        uint4 v = xp[(size_t)srcs[j] * 16 + lane];
        acc[0] += bf16_to_f(v.x & 0xFFFFu); acc[1] += bf16_to_f(v.x >> 16);
        acc[2] += bf16_to_f(v.y & 0xFFFFu); acc[3] += bf16_to_f(v.y >> 16);
        acc[4] += bf16_to_f(v.z & 0xFFFFu); acc[5] += bf16_to_f(v.z >> 16);
        acc[6] += bf16_to_f(v.w & 0xFFFFu); acc[7] += bf16_to_f(v.w >> 16);
    }
    float inv = (end > beg) ? 1.0f / (float)(end - beg) : 0.0f;
    uint4 o;
    o.x = (unsigned)f_to_bf16(acc[0] * inv) | ((unsigned)f_to_bf16(acc[1] * inv) << 16);
    o.y = (unsigned)f_to_bf16(acc[2] * inv) | ((unsigned)f_to_bf16(acc[3] * inv) << 16);
    o.z = (unsigned)f_to_bf16(acc[4] * inv) | ((unsigned)f_to_bf16(acc[5] * inv) << 16);
    o.w = (unsigned)f_to_bf16(acc[6] * inv) | ((unsigned)f_to_bf16(acc[7] * inv) << 16);
    ((uint4*)meanb)[(size_t)node * 16 + lane] = o;
}

// ---------------- fused dual GEMM: out = mean@Wl^T + x@Wr^T + b (+relu) ----------------
__global__ __launch_bounds__(256)
void gemm_kernel(const unsigned short* __restrict__ meanb, const unsigned short* __restrict__ xb,
                 const float* __restrict__ Wl, const float* __restrict__ bl,
                 const float* __restrict__ Wr, unsigned short* __restrict__ outb,
                 int N, int relu) {
    __shared__ float Wt[KT][D + 4];
    __shared__ float At[KT][NPB + 4];

    const int tid = threadIdx.x;
    const int c4 = (tid & 31) * 4;
    const int jg = tid >> 5;
    const int node0 = blockIdx.x * NPB;

    float acc[8][4];
#pragma unroll
    for (int j = 0; j < 8; ++j)
#pragma unroll
        for (int c = 0; c < 4; ++c) acc[j][c] = 0.f;

    for (int kt = 0; kt < 2 * D; kt += KT) {
        const float* W = (kt < D) ? Wl : Wr;
        const unsigned short* A = (kt < D) ? meanb : xb;
        const int k0 = (kt < D) ? kt : (kt - D);

        for (int i = tid; i < KT * D; i += 256) {
            int kk = i & (KT - 1);
            int cc = i >> 5;
            Wt[kk][cc] = W[(size_t)cc * D + k0 + kk];
        }
        for (int i = tid; i < KT * NPB; i += 256) {
            int kk = i & (KT - 1);
            int j = i >> 5;
            int n = node0 + j;
            At[kk][j] = (n < N) ? bf16_to_f(A[(size_t)n * D + k0 + kk]) : 0.f;
        }
        __syncthreads();

        for (int kk = 0; kk < KT; ++kk) {
            float4 w = *(const float4*)&Wt[kk][c4];
            float4 a0 = *(const float4*)&At[kk][jg * 8];
            float4 a1 = *(const float4*)&At[kk][jg * 8 + 4];
            float av[8] = {a0.x, a0.y, a0.z, a0.w, a1.x, a1.y, a1.z, a1.w};
#pragma unroll
            for (int j2 = 0; j2 < 8; ++j2) {
                acc[j2][0] += av[j2] * w.x;
                acc[j2][1] += av[j2] * w.y;
                acc[j2][2] += av[j2] * w.z;
                acc[j2][3] += av[j2] * w.w;
            }
        }
        __syncthreads();
    }

    float4 b = *(const float4*)&bl[c4];
#pragma unroll
    for (int j2 = 0; j2 < 8; ++j2) {
        int n = node0 + jg * 8 + j2;
        if (n < N) {
            float v0 = acc[j2][0] + b.x;
            float v1 = acc[j2][1] + b.y;
            float v2 = acc[j2][2] + b.z;
            float v3 = acc[j2][3] + b.w;
            if (relu) {
                v0 = fmaxf(v0, 0.f); v1 = fmaxf(v1, 0.f);
                v2 = fmaxf(v2, 0.f); v3 = fmaxf(v3, 0.f);
            }
            uint2 o;
            o.x = (unsigned)f_to_bf16(v0) | ((unsigned)f_to_bf16(v1) << 16);
            o.y = (unsigned)f_to_bf16(v2) | ((unsigned)f_to_bf16(v3) << 16);
            *(uint2*)&outb[(size_t)n * D + c4] = o;
        }
    }
}

// ---------------- column-wise min reduction ----------------
__global__ void min1_kernel(const unsigned short* __restrict__ xb, float* __restrict__ partial, int N) {
    int col = threadIdx.x;
    float m = 3.402823466e38f;
    for (int n = blockIdx.x; n < N; n += gridDim.x)
        m = fminf(m, bf16_to_f(xb[(size_t)n * D + col]));
    partial[(size_t)blockIdx.x * D + col] = m;
}

__global__ void min2_kernel(const float* __restrict__ partial, const int* __restrict__ flag,
                            void* __restrict__ out) {
    int col = threadIdx.x;
    float m = 3.402823466e38f;
    for (int b = 0; b < MIN_BLOCKS; ++b)
        m = fminf(m, partial[(size_t)b * D + col]);
    if (flag[1]) ((unsigned short*)out)[col] = f_to_bf16(m);
    else         ((float*)out)[col] = m;
}

// ---------------- launch ----------------
extern "C" void kernel_launch(void* const* d_in, const int* in_sizes, int n_in,
                              void* d_out, int out_size, void* d_ws, size_t ws_size,
                              hipStream_t stream) {
    const void* x0   = d_in[0];
    const void* eidx = d_in[1];
    const void* Wl0  = d_in[2];
    const void* bl0  = d_in[3];
    const void* Wr0  = d_in[4];

    const int N = in_sizes[0] / D;          // 100000
    const int E = in_sizes[1] / 2;          // 1600000
    const int L = in_sizes[2] / (D * D);    // 3

    char* ws = (char*)d_ws;
    size_t off = 0;
    auto alloc = [&](size_t bytes) -> void* {
        void* p = ws + off;
        off += (bytes + 255) & ~(size_t)255;
        return p;
    };
    unsigned short* xb    = (unsigned short*)alloc((size_t)N * D * 2);
    unsigned short* bufA  = (unsigned short*)alloc((size_t)N * D * 2);
    unsigned short* meanb = (unsigned short*)alloc((size_t)N * D * 2);
    int*   cnt     = (int*)alloc((size_t)N * sizeof(int));
    int*   offsets = (int*)alloc((size_t)(N + 1) * sizeof(int));
    int*   cursor  = (int*)alloc((size_t)N * sizeof(int));
    int*   srcs    = (int*)alloc((size_t)E * sizeof(int));
    int*   flag    = (int*)alloc(256);
    int*   blockSums = (int*)alloc(1024);
    float* Wlf     = (float*)alloc((size_t)L * D * D * sizeof(float));
    float* blf     = (float*)alloc((size_t)L * D * sizeof(float));
    float* Wrf     = (float*)alloc((size_t)L * D * D * sizeof(float));
    float* partial = (float*)alloc((size_t)MIN_BLOCKS * D * sizeof(float));
    (void)ws_size; (void)n_in; (void)out_size;

    hipMemsetAsync(cnt, 0, (size_t)N * sizeof(int), stream);

    detect_kernel<<<1, 1, 0, stream>>>((const unsigned short*)x0, (const int*)eidx, flag);

    cvt_x_kernel<<<2048, 256, 0, stream>>>(x0, flag, xb, N * D);
    cvt_f_kernel<<<256, 256, 0, stream>>>(Wl0, flag, Wlf, L * D * D);
    cvt_f_kernel<<<8, 256, 0, stream>>>(bl0, flag, blf, L * D);
    cvt_f_kernel<<<256, 256, 0, stream>>>(Wr0, flag, Wrf, L * D * D);

    hist_kernel<<<(E + 255) / 256, 256, 0, stream>>>(eidx, flag, cnt, E, N);

    const int nb = (N + SCAN_C - 1) / SCAN_C;   // 196 <= 256
    scan1_kernel<<<nb, 256, 0, stream>>>(cnt, blockSums, N);
    scan2_kernel<<<1, 256, 0, stream>>>(blockSums, nb);
    scan3_kernel<<<nb, 256, 0, stream>>>(cnt, blockSums, offsets, cursor, N, E);

    fill_kernel<<<(E + 255) / 256, 256, 0, stream>>>(eidx, flag, cursor, srcs, E, N);

    unsigned short* cur = xb;
    unsigned short* nxt = bufA;
    for (int l = 0; l < L; ++l) {
        int agg_blocks = (N * 16 + 255) / 256;
        agg_kernel<<<agg_blocks, 256, 0, stream>>>(cur, offsets, srcs, meanb, N);
        gemm_kernel<<<(N + NPB - 1) / NPB, 256, 0, stream>>>(
            meanb, cur, Wlf + (size_t)l * D * D, blf + (size_t)l * D,
            Wrf + (size_t)l * D * D, nxt, N, (l < L - 1) ? 1 : 0);
        unsigned short* t = cur; cur = nxt; nxt = t;
    }

    min1_kernel<<<MIN_BLOCKS, D, 0, stream>>>(cur, partial, N);
    min2_kernel<<<1, D, 0, stream>>>(partial, flag, (void*)d_out);
}

// Round 4
// 767.418 us; speedup vs baseline: 1.5714x; 1.2809x over previous
//
#include <hip/hip_runtime.h>
#include <hip/hip_bf16.h>

#define D 128
#define MIN_BLOCKS 512
#define SCAN_C 512

typedef __attribute__((ext_vector_type(8))) short bf16x8;
typedef __attribute__((ext_vector_type(4))) float f32x4;

// ---------------- bf16 helpers (manual, RN-even) ----------------
__device__ __forceinline__ float bf16_to_f(unsigned int u) {
    union { unsigned int i; float f; } c; c.i = u << 16; return c.f;
}
__device__ __forceinline__ unsigned short f_to_bf16(float f) {
    union { float f; unsigned int i; } c; c.f = f;
    unsigned int r = c.i + 0x7FFFu + ((c.i >> 16) & 1u);
    return (unsigned short)(r >> 16);
}

// ---------------- runtime dtype detection ----------------
__global__ void detect_kernel(const unsigned short* __restrict__ xr,
                              const int* __restrict__ er, int* __restrict__ flag) {
    int plaus = 0;
    for (int i = 0; i < 64; ++i) {
        unsigned short u = xr[2 * i];
        int e = (u >> 7) & 0xFF;
        if (e >= 0x74 && e <= 0x82) plaus++;
    }
    flag[1] = (plaus >= 32) ? 1 : 0;
    int zeros = 0;
    for (int i = 1; i < 128; i += 2) zeros += (er[i] == 0);
    flag[0] = (zeros >= 60) ? 1 : 0;
}

__device__ __forceinline__ int load_idx(const void* p, long long i, int is64) {
    if (is64) return (int)((const long long*)p)[i];
    return ((const int*)p)[i];
}

// ---------------- conversions ----------------
__global__ void cvt_x_kernel(const void* __restrict__ src, const int* __restrict__ flag,
                             unsigned short* __restrict__ dst, int n) {
    int is_bf16 = flag[1];
    int i = blockIdx.x * blockDim.x + threadIdx.x;
    int stride = gridDim.x * blockDim.x;
    if (is_bf16) {
        const unsigned short* s = (const unsigned short*)src;
        for (; i < n; i += stride) dst[i] = s[i];
    } else {
        const float* s = (const float*)src;
        for (; i < n; i += stride) dst[i] = f_to_bf16(s[i]);
    }
}

__global__ void cvt_f_kernel(const void* __restrict__ src, const int* __restrict__ flag,
                             float* __restrict__ dst, int n) {
    int is_bf16 = flag[1];
    int i = blockIdx.x * blockDim.x + threadIdx.x;
    int stride = gridDim.x * blockDim.x;
    if (is_bf16) {
        const unsigned short* s = (const unsigned short*)src;
        for (; i < n; i += stride) dst[i] = bf16_to_f(s[i]);
    } else {
        const float* s = (const float*)src;
        for (; i < n; i += stride) dst[i] = s[i];
    }
}

// ---------------- pack W into MFMA B-fragment order ----------------
// Wpack[layer][(nt*8+ks)*64+lane][j] = Wcat[n][k], n=nt*16+(lane&15), k=ks*32+(lane>>4)*8+j
__global__ void packW_kernel(const void* __restrict__ Wl0, const void* __restrict__ Wr0,
                             const int* __restrict__ flag, unsigned short* __restrict__ Wpack,
                             int L) {
    int idx = blockIdx.x * blockDim.x + threadIdx.x;
    if (idx >= L * 8 * 8 * 64) return;
    int lane = idx & 63;
    int ks = (idx >> 6) & 7;
    int nt = (idx >> 9) & 7;
    int layer = idx >> 12;
    int n = nt * 16 + (lane & 15);
    int k0 = ks * 32 + (lane >> 4) * 8;
    int is_bf16 = flag[1];
    unsigned short outv[8];
#pragma unroll
    for (int j = 0; j < 8; ++j) {
        int k = k0 + j;
        size_t off = (size_t)layer * D * D + (size_t)n * D + (k & 127);
        float v;
        if (is_bf16) {
            const unsigned short* W = (const unsigned short*)((k < D) ? Wl0 : Wr0);
            v = bf16_to_f(W[off]);
        } else {
            const float* W = (const float*)((k < D) ? Wl0 : Wr0);
            v = W[off];
        }
        outv[j] = f_to_bf16(v);
    }
    *(uint4*)&Wpack[(size_t)idx * 8] = *(uint4*)outv;
}

// ---------------- CSR build ----------------
__global__ void hist_kernel(const void* __restrict__ eidx, const int* __restrict__ flag,
                            int* __restrict__ cnt, int E, int N) {
    int is64 = flag[0];
    int e = blockIdx.x * blockDim.x + threadIdx.x;
    if (e < E) {
        int d = load_idx(eidx, (long long)E + e, is64);
        if ((unsigned)d < (unsigned)N) atomicAdd(&cnt[d], 1);
    }
}

__global__ void scan1_kernel(const int* __restrict__ cnt, int* __restrict__ blockSums, int N) {
    __shared__ int red[256];
    int base = blockIdx.x * SCAN_C;
    int t = threadIdx.x;
    int s = 0;
    if (base + t < N) s += cnt[base + t];
    if (base + t + 256 < N) s += cnt[base + t + 256];
    red[t] = s;
    __syncthreads();
    for (int off = 128; off > 0; off >>= 1) {
        if (t < off) red[t] += red[t + off];
        __syncthreads();
    }
    if (t == 0) blockSums[blockIdx.x] = red[0];
}

__global__ void scan2_kernel(int* __restrict__ blockSums, int nb) {
    __shared__ int sh[256];
    int t = threadIdx.x;
    int orig = (t < nb) ? blockSums[t] : 0;
    sh[t] = orig;
    __syncthreads();
    for (int off = 1; off < 256; off <<= 1) {
        int v = (t >= off) ? sh[t - off] : 0;
        __syncthreads();
        sh[t] += v;
        __syncthreads();
    }
    if (t < nb) blockSums[t] = sh[t] - orig;
}

__global__ void scan3_kernel(const int* __restrict__ cnt, const int* __restrict__ blockBase,
                             int* __restrict__ offsets, int* __restrict__ cursor, int N, int E) {
    __shared__ int sh[SCAN_C];
    int base = blockIdx.x * SCAN_C;
    int t = threadIdx.x;
    int v0 = (base + t < N) ? cnt[base + t] : 0;
    int v1 = (base + t + 256 < N) ? cnt[base + t + 256] : 0;
    sh[t] = v0;
    sh[t + 256] = v1;
    __syncthreads();
    for (int off = 1; off < SCAN_C; off <<= 1) {
        int a = (t >= off) ? sh[t - off] : 0;
        int b = (t + 256 >= off) ? sh[t + 256 - off] : 0;
        __syncthreads();
        sh[t] += a;
        sh[t + 256] += b;
        __syncthreads();
    }
    int bb = blockBase[blockIdx.x];
    if (base + t < N) {
        int e = bb + sh[t] - v0;
        offsets[base + t] = e;
        cursor[base + t] = e;
    }
    if (base + t + 256 < N) {
        int e = bb + sh[t + 256] - v1;
        offsets[base + t + 256] = e;
        cursor[base + t + 256] = e;
    }
    if (blockIdx.x == 0 && t == 0) offsets[N] = E;
}

__global__ void fill_kernel(const void* __restrict__ eidx, const int* __restrict__ flag,
                            int* __restrict__ cursor, int* __restrict__ srcs_sorted,
                            int E, int N) {
    int is64 = flag[0];
    int e = blockIdx.x * blockDim.x + threadIdx.x;
    if (e < E) {
        int s = load_idx(eidx, e, is64);
        int d = load_idx(eidx, (long long)E + e, is64);
        if ((unsigned)d < (unsigned)N) {
            int p = atomicAdd(&cursor[d], 1);
            srcs_sorted[p] = s;
        }
    }
}

// ---------------- mean aggregation (gather via CSR), bf16 rows ----------------
__global__ void agg_kernel(const unsigned short* __restrict__ xb, const int* __restrict__ offsets,
                           const int* __restrict__ srcs, unsigned short* __restrict__ meanb, int N) {
    int g = blockIdx.x * blockDim.x + threadIdx.x;
    int node = g >> 4;
    int lane = g & 15;
    if (node >= N) return;
    int beg = offsets[node], end = offsets[node + 1];
    float acc[8];
#pragma unroll
    for (int i = 0; i < 8; ++i) acc[i] = 0.f;
    const uint4* xp = (const uint4*)xb;
    for (int j = beg; j < end; ++j) {
        uint4 v = xp[(size_t)srcs[j] * 16 + lane];
        acc[0] += bf16_to_f(v.x & 0xFFFFu); acc[1] += bf16_to_f(v.x >> 16);
        acc[2] += bf16_to_f(v.y & 0xFFFFu); acc[3] += bf16_to_f(v.y >> 16);
        acc[4] += bf16_to_f(v.z & 0xFFFFu); acc[5] += bf16_to_f(v.z >> 16);
        acc[6] += bf16_to_f(v.w & 0xFFFFu); acc[7] += bf16_to_f(v.w >> 16);
    }
    float inv = (end > beg) ? 1.0f / (float)(end - beg) : 0.0f;
    uint4 o;
    o.x = (unsigned)f_to_bf16(acc[0] * inv) | ((unsigned)f_to_bf16(acc[1] * inv) << 16);
    o.y = (unsigned)f_to_bf16(acc[2] * inv) | ((unsigned)f_to_bf16(acc[3] * inv) << 16);
    o.z = (unsigned)f_to_bf16(acc[4] * inv) | ((unsigned)f_to_bf16(acc[5] * inv) << 16);
    o.w = (unsigned)f_to_bf16(acc[6] * inv) | ((unsigned)f_to_bf16(acc[7] * inv) << 16);
    ((uint4*)meanb)[(size_t)node * 16 + lane] = o;
}

// ---------------- MFMA dual GEMM: out = [mean|x] @ [Wl|Wr]^T + b (+relu) ----------------
// Block 256 thr (4 waves), 64 nodes. Wave: 16 nodes x 128 cols, 8 accs.
__global__ __launch_bounds__(256)
void gemm_mfma_kernel(const unsigned short* __restrict__ meanb, const unsigned short* __restrict__ xb,
                      const unsigned short* __restrict__ Wpack, const float* __restrict__ bl,
                      unsigned short* __restrict__ outb, int N, int relu) {
    __shared__ unsigned short Atile[64][264];   // 64 rows x 256 k (bf16), +8 pad; reused for out staging

    const int tid = threadIdx.x;
    const int wave = tid >> 6;
    const int lane = tid & 63;
    const int m16 = lane & 15;
    const int quad = lane >> 4;
    const int node0 = blockIdx.x * 64;

    // stage A = [mean | x] rows into LDS
    {
        const uint4* mp = (const uint4*)meanb;
        const uint4* xp = (const uint4*)xb;
        for (int i = tid; i < 64 * 32; i += 256) {
            int row = i >> 5;
            int c = i & 31;           // uint4 within 256-k row
            int n = node0 + row;
            uint4 v = make_uint4(0u, 0u, 0u, 0u);
            if (n < N) v = (c < 16) ? mp[(size_t)n * 16 + c] : xp[(size_t)n * 16 + (c - 16)];
            *(uint4*)&Atile[row][c * 8] = v;
        }
    }
    __syncthreads();

    f32x4 acc[8];
#pragma unroll
    for (int i = 0; i < 8; ++i) acc[i] = (f32x4)0.0f;

    const bf16x8* wp = (const bf16x8*)Wpack;
    const int arow = wave * 16 + m16;

#pragma unroll
    for (int ks = 0; ks < 8; ++ks) {
        bf16x8 afrag = *(const bf16x8*)&Atile[arow][ks * 32 + quad * 8];
#pragma unroll
        for (int nt = 0; nt < 8; ++nt) {
            bf16x8 bfrag = wp[(nt * 8 + ks) * 64 + lane];
            acc[nt] = __builtin_amdgcn_mfma_f32_16x16x32_bf16(afrag, bfrag, acc[nt], 0, 0, 0);
        }
    }
    __syncthreads();

    // epilogue: bias + relu, bf16 into LDS (row m, col n), then coalesced store
#pragma unroll
    for (int nt = 0; nt < 8; ++nt) {
        int n = nt * 16 + m16;
        float b = bl[n];
#pragma unroll
        for (int r = 0; r < 4; ++r) {
            int m = wave * 16 + quad * 4 + r;
            float v = acc[nt][r] + b;
            if (relu) v = fmaxf(v, 0.f);
            Atile[m][n] = f_to_bf16(v);
        }
    }
    __syncthreads();

    for (int i = tid; i < 64 * 16; i += 256) {
        int row = i >> 4;
        int c = i & 15;
        int n = node0 + row;
        if (n < N) ((uint4*)outb)[(size_t)n * 16 + c] = *(uint4*)&Atile[row][c * 8];
    }
}

// ---------------- column-wise min reduction ----------------
__global__ void min1_kernel(const unsigned short* __restrict__ xb, float* __restrict__ partial, int N) {
    int col = threadIdx.x;
    float m = 3.402823466e38f;
    for (int n = blockIdx.x; n < N; n += gridDim.x)
        m = fminf(m, bf16_to_f(xb[(size_t)n * D + col]));
    partial[(size_t)blockIdx.x * D + col] = m;
}

__global__ void min2_kernel(const float* __restrict__ partial, const int* __restrict__ flag,
                            void* __restrict__ out) {
    int col = threadIdx.x;
    float m = 3.402823466e38f;
    for (int b = 0; b < MIN_BLOCKS; ++b)
        m = fminf(m, partial[(size_t)b * D + col]);
    if (flag[1]) ((unsigned short*)out)[col] = f_to_bf16(m);
    else         ((float*)out)[col] = m;
}

// ---------------- launch ----------------
extern "C" void kernel_launch(void* const* d_in, const int* in_sizes, int n_in,
                              void* d_out, int out_size, void* d_ws, size_t ws_size,
                              hipStream_t stream) {
    const void* x0   = d_in[0];
    const void* eidx = d_in[1];
    const void* Wl0  = d_in[2];
    const void* bl0  = d_in[3];
    const void* Wr0  = d_in[4];

    const int N = in_sizes[0] / D;          // 100000
    const int E = in_sizes[1] / 2;          // 1600000
    const int L = in_sizes[2] / (D * D);    // 3

    char* ws = (char*)d_ws;
    size_t off = 0;
    auto alloc = [&](size_t bytes) -> void* {
        void* p = ws + off;
        off += (bytes + 255) & ~(size_t)255;
        return p;
    };
    unsigned short* xb    = (unsigned short*)alloc((size_t)N * D * 2);
    unsigned short* bufA  = (unsigned short*)alloc((size_t)N * D * 2);
    unsigned short* meanb = (unsigned short*)alloc((size_t)N * D * 2);
    int*   cnt     = (int*)alloc((size_t)N * sizeof(int));
    int*   offsets = (int*)alloc((size_t)(N + 1) * sizeof(int));
    int*   cursor  = (int*)alloc((size_t)N * sizeof(int));
    int*   srcs    = (int*)alloc((size_t)E * sizeof(int));
    int*   flag    = (int*)alloc(256);
    int*   blockSums = (int*)alloc(1024);
    unsigned short* Wpack = (unsigned short*)alloc((size_t)L * 8 * 8 * 64 * 8 * 2);
    float* blf     = (float*)alloc((size_t)L * D * sizeof(float));
    float* partial = (float*)alloc((size_t)MIN_BLOCKS * D * sizeof(float));
    (void)ws_size; (void)n_in; (void)out_size;

    hipMemsetAsync(cnt, 0, (size_t)N * sizeof(int), stream);

    detect_kernel<<<1, 1, 0, stream>>>((const unsigned short*)x0, (const int*)eidx, flag);

    cvt_x_kernel<<<2048, 256, 0, stream>>>(x0, flag, xb, N * D);
    cvt_f_kernel<<<8, 256, 0, stream>>>(bl0, flag, blf, L * D);
    packW_kernel<<<(L * 8 * 8 * 64 + 255) / 256, 256, 0, stream>>>(Wl0, Wr0, flag, Wpack, L);

    hist_kernel<<<(E + 255) / 256, 256, 0, stream>>>(eidx, flag, cnt, E, N);

    const int nb = (N + SCAN_C - 1) / SCAN_C;
    scan1_kernel<<<nb, 256, 0, stream>>>(cnt, blockSums, N);
    scan2_kernel<<<1, 256, 0, stream>>>(blockSums, nb);
    scan3_kernel<<<nb, 256, 0, stream>>>(cnt, blockSums, offsets, cursor, N, E);

    fill_kernel<<<(E + 255) / 256, 256, 0, stream>>>(eidx, flag, cursor, srcs, E, N);

    unsigned short* cur = xb;
    unsigned short* nxt = bufA;
    for (int l = 0; l < L; ++l) {
        int agg_blocks = (N * 16 + 255) / 256;
        agg_kernel<<<agg_blocks, 256, 0, stream>>>(cur, offsets, srcs, meanb, N);
        gemm_mfma_kernel<<<(N + 63) / 64, 256, 0, stream>>>(
            meanb, cur, Wpack + (size_t)l * 8 * 8 * 64 * 8, blf + (size_t)l * D,
            nxt, N, (l < L - 1) ? 1 : 0);
        unsigned short* t = cur; cur = nxt; nxt = t;
    }

    min1_kernel<<<MIN_BLOCKS, D, 0, stream>>>(cur, partial, N);
    min2_kernel<<<1, D, 0, stream>>>(partial, flag, (void*)d_out);
}

// Round 5
// 625.436 us; speedup vs baseline: 1.9281x; 1.2270x over previous
//
#include <hip/hip_runtime.h>
#include <hip/hip_bf16.h>

#define D 128
#define MIN_BLOCKS 512
#define SCAN_C 512
#define BKT 512        // nodes per bucket
#define BKT_SHIFT 9
#define CH 256         // edge chunks
#define NBMAX 512

typedef __attribute__((ext_vector_type(8))) short bf16x8;
typedef __attribute__((ext_vector_type(4))) float f32x4;

// ---------------- bf16 helpers (manual, RN-even) ----------------
__device__ __forceinline__ float bf16_to_f(unsigned int u) {
    union { unsigned int i; float f; } c; c.i = u << 16; return c.f;
}
__device__ __forceinline__ unsigned short f_to_bf16(float f) {
    union { float f; unsigned int i; } c; c.f = f;
    unsigned int r = c.i + 0x7FFFu + ((c.i >> 16) & 1u);
    return (unsigned short)(r >> 16);
}

// ---------------- runtime dtype detection ----------------
__global__ void detect_kernel(const unsigned short* __restrict__ xr,
                              const int* __restrict__ er, int* __restrict__ flag) {
    int plaus = 0;
    for (int i = 0; i < 64; ++i) {
        unsigned short u = xr[2 * i];
        int e = (u >> 7) & 0xFF;
        if (e >= 0x74 && e <= 0x82) plaus++;
    }
    flag[1] = (plaus >= 32) ? 1 : 0;
    int zeros = 0;
    for (int i = 1; i < 128; i += 2) zeros += (er[i] == 0);
    flag[0] = (zeros >= 60) ? 1 : 0;
}

__device__ __forceinline__ int load_idx(const void* p, long long i, int is64) {
    if (is64) return (int)((const long long*)p)[i];
    return ((const int*)p)[i];
}

// ---------------- conversions ----------------
__global__ void cvt_x_kernel(const void* __restrict__ src, const int* __restrict__ flag,
                             unsigned short* __restrict__ dst, int n) {
    int is_bf16 = flag[1];
    int i = blockIdx.x * blockDim.x + threadIdx.x;
    int stride = gridDim.x * blockDim.x;
    if (is_bf16) {
        const unsigned short* s = (const unsigned short*)src;
        for (; i < n; i += stride) dst[i] = s[i];
    } else {
        const float* s = (const float*)src;
        for (; i < n; i += stride) dst[i] = f_to_bf16(s[i]);
    }
}

__global__ void cvt_f_kernel(const void* __restrict__ src, const int* __restrict__ flag,
                             float* __restrict__ dst, int n) {
    int is_bf16 = flag[1];
    int i = blockIdx.x * blockDim.x + threadIdx.x;
    int stride = gridDim.x * blockDim.x;
    if (is_bf16) {
        const unsigned short* s = (const unsigned short*)src;
        for (; i < n; i += stride) dst[i] = bf16_to_f(s[i]);
    } else {
        const float* s = (const float*)src;
        for (; i < n; i += stride) dst[i] = s[i];
    }
}

// ---------------- pack W into MFMA B-fragment order ----------------
__global__ void packW_kernel(const void* __restrict__ Wl0, const void* __restrict__ Wr0,
                             const int* __restrict__ flag, unsigned short* __restrict__ Wpack,
                             int L) {
    int idx = blockIdx.x * blockDim.x + threadIdx.x;
    if (idx >= L * 8 * 8 * 64) return;
    int lane = idx & 63;
    int ks = (idx >> 6) & 7;
    int nt = (idx >> 9) & 7;
    int layer = idx >> 12;
    int n = nt * 16 + (lane & 15);
    int k0 = ks * 32 + (lane >> 4) * 8;
    int is_bf16 = flag[1];
    unsigned short outv[8];
#pragma unroll
    for (int j = 0; j < 8; ++j) {
        int k = k0 + j;
        size_t off = (size_t)layer * D * D + (size_t)n * D + (k & 127);
        float v;
        if (is_bf16) {
            const unsigned short* W = (const unsigned short*)((k < D) ? Wl0 : Wr0);
            v = bf16_to_f(W[off]);
        } else {
            const float* W = (const float*)((k < D) ? Wl0 : Wr0);
            v = W[off];
        }
        outv[j] = f_to_bf16(v);
    }
    *(uint4*)&Wpack[(size_t)idx * 8] = *(uint4*)outv;
}

// ---------------- bucketed CSR build ----------------
// A1: per-chunk histogram of destination buckets
__global__ void bucket_hist_kernel(const void* __restrict__ eidx, const int* __restrict__ flag,
                                   int* __restrict__ counts2D, int E, int NB, int EPC) {
    __shared__ int hist[NBMAX];
    int c = blockIdx.x;
    for (int i = threadIdx.x; i < NB; i += blockDim.x) hist[i] = 0;
    __syncthreads();
    int is64 = flag[0];
    int end = min(E, (c + 1) * EPC);
    for (int e = c * EPC + threadIdx.x; e < end; e += blockDim.x) {
        int d = load_idx(eidx, (long long)E + e, is64);
        atomicAdd(&hist[d >> BKT_SHIFT], 1);
    }
    __syncthreads();
    for (int i = threadIdx.x; i < NB; i += blockDim.x)
        counts2D[i * CH + c] = hist[i];
}

// generic 3-phase exclusive scan
__global__ void gscan1_kernel(const int* __restrict__ in, int* __restrict__ blockSums, int n) {
    __shared__ int red[256];
    int base = blockIdx.x * SCAN_C;
    int t = threadIdx.x;
    int s = 0;
    if (base + t < n) s += in[base + t];
    if (base + t + 256 < n) s += in[base + t + 256];
    red[t] = s;
    __syncthreads();
    for (int off = 128; off > 0; off >>= 1) {
        if (t < off) red[t] += red[t + off];
        __syncthreads();
    }
    if (t == 0) blockSums[blockIdx.x] = red[0];
}

__global__ void gscan2_kernel(int* __restrict__ blockSums, int nb) {
    __shared__ int sh[256];
    int t = threadIdx.x;
    int orig = (t < nb) ? blockSums[t] : 0;
    sh[t] = orig;
    __syncthreads();
    for (int off = 1; off < 256; off <<= 1) {
        int v = (t >= off) ? sh[t - off] : 0;
        __syncthreads();
        sh[t] += v;
        __syncthreads();
    }
    if (t < nb) blockSums[t] = sh[t] - orig;
}

__global__ void gscan3_kernel(const int* __restrict__ in, const int* __restrict__ blockBase,
                              int* __restrict__ out, int n) {
    __shared__ int sh[SCAN_C];
    int base = blockIdx.x * SCAN_C;
    int t = threadIdx.x;
    int v0 = (base + t < n) ? in[base + t] : 0;
    int v1 = (base + t + 256 < n) ? in[base + t + 256] : 0;
    sh[t] = v0;
    sh[t + 256] = v1;
    __syncthreads();
    for (int off = 1; off < SCAN_C; off <<= 1) {
        int a = (t >= off) ? sh[t - off] : 0;
        int b = (t + 256 >= off) ? sh[t + 256 - off] : 0;
        __syncthreads();
        sh[t] += a;
        sh[t + 256] += b;
        __syncthreads();
    }
    int bb = blockBase[blockIdx.x];
    if (base + t < n) out[base + t] = bb + sh[t] - v0;
    if (base + t + 256 < n) out[base + t + 256] = bb + sh[t + 256] - v1;
}

// A2: scatter packed edges into (bucket, chunk) regions
__global__ void bucket_scatter_kernel(const void* __restrict__ eidx, const int* __restrict__ flag,
                                      const int* __restrict__ bases2D, unsigned int* __restrict__ ebuf,
                                      int E, int NB, int EPC) {
    __shared__ int cur[NBMAX];
    int c = blockIdx.x;
    for (int i = threadIdx.x; i < NB; i += blockDim.x) cur[i] = bases2D[i * CH + c];
    __syncthreads();
    int is64 = flag[0];
    int end = min(E, (c + 1) * EPC);
    for (int e = c * EPC + threadIdx.x; e < end; e += blockDim.x) {
        int s = load_idx(eidx, e, is64);
        int d = load_idx(eidx, (long long)E + e, is64);
        int b = d >> BKT_SHIFT;
        int pos = atomicAdd(&cur[b], 1);
        ebuf[pos] = ((unsigned)s << BKT_SHIFT) | (unsigned)(d & (BKT - 1));
    }
}

// B: per-bucket node offsets + ordered src list
__global__ __launch_bounds__(BKT)
void bucket_csr_kernel(const unsigned int* __restrict__ ebuf, const int* __restrict__ bases2D,
                       int* __restrict__ offsets, int* __restrict__ srcs, int E, int N, int NB) {
    __shared__ int lcnt[BKT];
    __shared__ int sh[BKT];
    __shared__ int lcur[BKT];
    int b = blockIdx.x;
    int t = threadIdx.x;
    int start = bases2D[b * CH];
    int end = (b + 1 < NB) ? bases2D[(b + 1) * CH] : E;
    lcnt[t] = 0;
    __syncthreads();
    for (int e = start + t; e < end; e += BKT)
        atomicAdd(&lcnt[ebuf[e] & (BKT - 1)], 1);
    __syncthreads();
    sh[t] = lcnt[t];
    __syncthreads();
    for (int off = 1; off < BKT; off <<= 1) {
        int v = (t >= off) ? sh[t - off] : 0;
        __syncthreads();
        sh[t] += v;
        __syncthreads();
    }
    int excl = sh[t] - lcnt[t];
    int node = b * BKT + t;
    if (node < N) offsets[node] = start + excl;
    lcur[t] = start + excl;
    __syncthreads();
    for (int e = start + t; e < end; e += BKT) {
        unsigned int p = ebuf[e];
        int pos = atomicAdd(&lcur[p & (BKT - 1)], 1);
        srcs[pos] = (int)(p >> BKT_SHIFT);
    }
    if (b == 0 && t == 0) offsets[N] = E;
}

// ---------------- mean aggregation (gather via CSR), bf16 rows ----------------
__global__ void agg_kernel(const unsigned short* __restrict__ xb, const int* __restrict__ offsets,
                           const int* __restrict__ srcs, unsigned short* __restrict__ meanb, int N) {
    int g = blockIdx.x * blockDim.x + threadIdx.x;
    int node = g >> 4;
    int lane = g & 15;
    if (node >= N) return;
    int beg = offsets[node], end = offsets[node + 1];
    float acc[8];
#pragma unroll
    for (int i = 0; i < 8; ++i) acc[i] = 0.f;
    const uint4* xp = (const uint4*)xb;
    for (int j = beg; j < end; ++j) {
        uint4 v = xp[(size_t)srcs[j] * 16 + lane];
        acc[0] += bf16_to_f(v.x & 0xFFFFu); acc[1] += bf16_to_f(v.x >> 16);
        acc[2] += bf16_to_f(v.y & 0xFFFFu); acc[3] += bf16_to_f(v.y >> 16);
        acc[4] += bf16_to_f(v.z & 0xFFFFu); acc[5] += bf16_to_f(v.z >> 16);
        acc[6] += bf16_to_f(v.w & 0xFFFFu); acc[7] += bf16_to_f(v.w >> 16);
    }
    float inv = (end > beg) ? 1.0f / (float)(end - beg) : 0.0f;
    uint4 o;
    o.x = (unsigned)f_to_bf16(acc[0] * inv) | ((unsigned)f_to_bf16(acc[1] * inv) << 16);
    o.y = (unsigned)f_to_bf16(acc[2] * inv) | ((unsigned)f_to_bf16(acc[3] * inv) << 16);
    o.z = (unsigned)f_to_bf16(acc[4] * inv) | ((unsigned)f_to_bf16(acc[5] * inv) << 16);
    o.w = (unsigned)f_to_bf16(acc[6] * inv) | ((unsigned)f_to_bf16(acc[7] * inv) << 16);
    ((uint4*)meanb)[(size_t)node * 16 + lane] = o;
}

// ---------------- MFMA dual GEMM: out = [mean|x] @ [Wl|Wr]^T + b (+relu) ----------------
__global__ __launch_bounds__(256)
void gemm_mfma_kernel(const unsigned short* __restrict__ meanb, const unsigned short* __restrict__ xb,
                      const unsigned short* __restrict__ Wpack, const float* __restrict__ bl,
                      unsigned short* __restrict__ outb, int N, int relu) {
    __shared__ unsigned short Atile[64][264];

    const int tid = threadIdx.x;
    const int wave = tid >> 6;
    const int lane = tid & 63;
    const int m16 = lane & 15;
    const int quad = lane >> 4;
    const int node0 = blockIdx.x * 64;

    {
        const uint4* mp = (const uint4*)meanb;
        const uint4* xp = (const uint4*)xb;
        for (int i = tid; i < 64 * 32; i += 256) {
            int row = i >> 5;
            int c = i & 31;
            int n = node0 + row;
            uint4 v = make_uint4(0u, 0u, 0u, 0u);
            if (n < N) v = (c < 16) ? mp[(size_t)n * 16 + c] : xp[(size_t)n * 16 + (c - 16)];
            *(uint4*)&Atile[row][c * 8] = v;
        }
    }
    __syncthreads();

    f32x4 acc[8];
#pragma unroll
    for (int i = 0; i < 8; ++i) acc[i] = (f32x4)0.0f;

    const bf16x8* wp = (const bf16x8*)Wpack;
    const int arow = wave * 16 + m16;

#pragma unroll
    for (int ks = 0; ks < 8; ++ks) {
        bf16x8 afrag = *(const bf16x8*)&Atile[arow][ks * 32 + quad * 8];
#pragma unroll
        for (int nt = 0; nt < 8; ++nt) {
            bf16x8 bfrag = wp[(nt * 8 + ks) * 64 + lane];
            acc[nt] = __builtin_amdgcn_mfma_f32_16x16x32_bf16(afrag, bfrag, acc[nt], 0, 0, 0);
        }
    }
    __syncthreads();

#pragma unroll
    for (int nt = 0; nt < 8; ++nt) {
        int n = nt * 16 + m16;
        float b = bl[n];
#pragma unroll
        for (int r = 0; r < 4; ++r) {
            int m = wave * 16 + quad * 4 + r;
            float v = acc[nt][r] + b;
            if (relu) v = fmaxf(v, 0.f);
            Atile[m][n] = f_to_bf16(v);
        }
    }
    __syncthreads();

    for (int i = tid; i < 64 * 16; i += 256) {
        int row = i >> 4;
        int c = i & 15;
        int n = node0 + row;
        if (n < N) ((uint4*)outb)[(size_t)n * 16 + c] = *(uint4*)&Atile[row][c * 8];
    }
}

// ---------------- column-wise min reduction ----------------
__global__ void min1_kernel(const unsigned short* __restrict__ xb, float* __restrict__ partial, int N) {
    int col = threadIdx.x;
    float m = 3.402823466e38f;
    for (int n = blockIdx.x; n < N; n += gridDim.x)
        m = fminf(m, bf16_to_f(xb[(size_t)n * D + col]));
    partial[(size_t)blockIdx.x * D + col] = m;
}

__global__ void min2_kernel(const float* __restrict__ partial, const int* __restrict__ flag,
                            void* __restrict__ out) {
    int col = threadIdx.x;
    float m = 3.402823466e38f;
    for (int b = 0; b < MIN_BLOCKS; ++b)
        m = fminf(m, partial[(size_t)b * D + col]);
    if (flag[1]) ((unsigned short*)out)[col] = f_to_bf16(m);
    else         ((float*)out)[col] = m;
}

// ---------------- launch ----------------
extern "C" void kernel_launch(void* const* d_in, const int* in_sizes, int n_in,
                              void* d_out, int out_size, void* d_ws, size_t ws_size,
                              hipStream_t stream) {
    const void* x0   = d_in[0];
    const void* eidx = d_in[1];
    const void* Wl0  = d_in[2];
    const void* bl0  = d_in[3];
    const void* Wr0  = d_in[4];

    const int N = in_sizes[0] / D;          // 100000
    const int E = in_sizes[1] / 2;          // 1600000
    const int L = in_sizes[2] / (D * D);    // 3

    char* ws = (char*)d_ws;
    size_t off = 0;
    auto alloc = [&](size_t bytes) -> void* {
        void* p = ws + off;
        off += (bytes + 255) & ~(size_t)255;
        return p;
    };
    unsigned short* xb    = (unsigned short*)alloc((size_t)N * D * 2);
    unsigned short* bufA  = (unsigned short*)alloc((size_t)N * D * 2);
    unsigned short* meanb = (unsigned short*)alloc((size_t)N * D * 2);
    int*   offsets = (int*)alloc((size_t)(N + 1) * sizeof(int));
    int*   srcs    = (int*)alloc((size_t)E * sizeof(int));
    int*   flag    = (int*)alloc(256);
    unsigned short* Wpack = (unsigned short*)alloc((size_t)L * 8 * 8 * 64 * 8 * 2);
    float* blf     = (float*)alloc((size_t)L * D * sizeof(float));
    float* partial = (float*)alloc((size_t)MIN_BLOCKS * D * sizeof(float));
    (void)ws_size; (void)n_in; (void)out_size;

    const int NB  = (N + BKT - 1) / BKT;     // 196
    const int EPC = (E + CH - 1) / CH;       // 6250
    const int n2  = NB * CH;                 // 50176
    // CSR-build scratch aliased into buffers not yet live:
    unsigned int* ebuf = (unsigned int*)meanb;            // E*4 = 6.4 MB <= 25.6 MB
    int* counts2D  = (int*)bufA;                          // n2*4 = 200 KB
    int* bases2D   = counts2D + n2;                       // 200 KB
    int* blockSums = bases2D + n2;                        // 1 KB

    detect_kernel<<<1, 1, 0, stream>>>((const unsigned short*)x0, (const int*)eidx, flag);

    cvt_x_kernel<<<2048, 256, 0, stream>>>(x0, flag, xb, N * D);
    cvt_f_kernel<<<8, 256, 0, stream>>>(bl0, flag, blf, L * D);
    packW_kernel<<<(L * 8 * 8 * 64 + 255) / 256, 256, 0, stream>>>(Wl0, Wr0, flag, Wpack, L);

    bucket_hist_kernel<<<CH, 256, 0, stream>>>(eidx, flag, counts2D, E, NB, EPC);
    const int nb2 = (n2 + SCAN_C - 1) / SCAN_C;   // 98
    gscan1_kernel<<<nb2, 256, 0, stream>>>(counts2D, blockSums, n2);
    gscan2_kernel<<<1, 256, 0, stream>>>(blockSums, nb2);
    gscan3_kernel<<<nb2, 256, 0, stream>>>(counts2D, blockSums, bases2D, n2);
    bucket_scatter_kernel<<<CH, 256, 0, stream>>>(eidx, flag, bases2D, ebuf, E, NB, EPC);
    bucket_csr_kernel<<<NB, BKT, 0, stream>>>(ebuf, bases2D, offsets, srcs, E, N, NB);

    unsigned short* cur = xb;
    unsigned short* nxt = bufA;
    for (int l = 0; l < L; ++l) {
        int agg_blocks = (N * 16 + 255) / 256;
        agg_kernel<<<agg_blocks, 256, 0, stream>>>(cur, offsets, srcs, meanb, N);
        gemm_mfma_kernel<<<(N + 63) / 64, 256, 0, stream>>>(
            meanb, cur, Wpack + (size_t)l * 8 * 8 * 64 * 8, blf + (size_t)l * D,
            nxt, N, (l < L - 1) ? 1 : 0);
        unsigned short* t = cur; cur = nxt; nxt = t;
    }

    min1_kernel<<<MIN_BLOCKS, D, 0, stream>>>(cur, partial, N);
    min2_kernel<<<1, D, 0, stream>>>(partial, flag, (void*)d_out);
}